// Round 10
// baseline (244.673 us; speedup 1.0000x reference)
//
#include <hip/hip_runtime.h>

// Flash attention, Q=K=V=x, row-mask. B=8, S=2048, D=512, fp32 in/out.
// R10 = R9's V-in-VGPR idea, but sized to fit 128 VGPR/wave (no spill):
// BM=32, BN=64, grid 512 (2 blocks/CU -> 4 waves/SIMD). Per wave:
// acc[2][4]=32 + q8=32 + vreg[2][4]=32 regs. K fp8 LDS dbuf (64rows x 512B),
// P LDS dbuf (32 x 144B, bank-clean), V global->VGPR (L2-resident).
// fp8 QK (pair-interleaved cols), fixed-m softmax, masked rows p=1.

constexpr int BATCH = 8;
constexpr int SEQ   = 2048;
constexpr int DIM   = 512;
constexpr int BM    = 32;
constexpr int BN    = 64;
constexpr int NIT   = SEQ / BN;     // 32

// LDS byte offsets
constexpr int KB0 = 0,     KB1 = 32768;     // fp8 Kt[64][512B]
constexpr int PB0 = 65536, PB1 = 70144;     // 32 rows x 144B
constexpr int LBO = 74752, LIO = 75264;
constexpr int LDS_TOTAL = 75392;

typedef float f4    __attribute__((ext_vector_type(4)));
typedef float f32x4 __attribute__((ext_vector_type(4)));
typedef short s16x8 __attribute__((ext_vector_type(8)));
typedef long  l2    __attribute__((ext_vector_type(2)));
typedef unsigned u32x2 __attribute__((ext_vector_type(2)));
typedef unsigned u32x4 __attribute__((ext_vector_type(4)));

#define AS1 __attribute__((address_space(1)))
#define AS3 __attribute__((address_space(3)))

__device__ __forceinline__ unsigned bfr(float x) {   // f32 -> bf16 (RNE)
    unsigned u = __float_as_uint(x);
    return (u + 0x7FFFu + ((u >> 16) & 1u)) >> 16;
}
__device__ __forceinline__ unsigned pk2(float a, float b) {
    return bfr(a) | (bfr(b) << 16);
}
__device__ __forceinline__ void gload_lds16(const void* g, void* l) {
    __builtin_amdgcn_global_load_lds((const AS1 void*)g, (AS3 void*)l, 16, 0, 0);
}
__device__ __forceinline__ float fp8_dec(unsigned byte) {  // e4m3fn -> f32
    const unsigned e = (byte >> 3) & 15u, m = byte & 7u;
    return e ? __uint_as_float(((byte & 128u) << 24) | ((e + 120u) << 23) | (m << 20))
             : 0.f;
}

// ---------------- prep: fp32 -> fp8 (k-pair-interleaved) + bf16 transposed ----
__global__ __launch_bounds__(256)
void prep_kernel(const float* __restrict__ x, unsigned char* __restrict__ xq,
                 unsigned short* __restrict__ xt) {
    __shared__ __align__(16) unsigned short tile[64 * 66];
    const int t   = threadIdx.x;
    const int bid = blockIdx.x;          // 2048 = 8 b * 32 s-tiles * 8 d-tiles
    const int b   = bid >> 8;
    const int rr  = bid & 255;
    const int s0  = (rr >> 3) * 64;
    const int d0  = (rr & 7) * 64;
    const float* xb = x + (size_t)b * SEQ * DIM;

    const int sl = t >> 4, c4 = t & 15;
    // column-permuted fp8 offset for k0 = d0 + c4*4 (e0 in {0,4})
    const int k0 = d0 + c4 * 4;
    const int kk = k0 >> 5, gg = (k0 >> 3) & 3, e0 = k0 & 7;
    const int cp = (kk >> 1) * 64 + gg * 16 + (kk & 1) * 8 + e0;

    #pragma unroll
    for (int k = 0; k < 4; ++k) {
        const int s = sl + k * 16;
        f4 v = *(const f4*)(xb + (size_t)(s0 + s) * DIM + k0);
        int r = __builtin_amdgcn_cvt_pk_fp8_f32(v[0], v[1], 0, false);
        r     = __builtin_amdgcn_cvt_pk_fp8_f32(v[2], v[3], r, true);
        *(int*)(xq + (size_t)(b * SEQ + s0 + s) * 512 + cp) = r;
        tile[(c4 * 4 + 0) * 66 + s] = (unsigned short)bfr(v[0]);
        tile[(c4 * 4 + 1) * 66 + s] = (unsigned short)bfr(v[1]);
        tile[(c4 * 4 + 2) * 66 + s] = (unsigned short)bfr(v[2]);
        tile[(c4 * 4 + 3) * 66 + s] = (unsigned short)bfr(v[3]);
    }
    __syncthreads();
    const int dl = t >> 2, sb = t & 3;
    const unsigned* lp = (const unsigned*)&tile[dl * 66 + sb * 16];
    unsigned short* op = xt + ((size_t)b * DIM + d0 + dl) * SEQ + s0 + sb * 16;
    u32x4 a, c;
    a[0] = lp[0]; a[1] = lp[1]; a[2] = lp[2]; a[3] = lp[3];
    c[0] = lp[4]; c[1] = lp[5]; c[2] = lp[6]; c[3] = lp[7];
    *(u32x4*)op = a;
    *(u32x4*)(op + 8) = c;
}

// ---------------- main attention kernel ----------------
__global__ __launch_bounds__(512, 4)
void attn_fwd(const unsigned char* __restrict__ xq,
              const unsigned short* __restrict__ xt,
              const int* __restrict__ mask,
              float* __restrict__ out) {
    extern __shared__ __align__(16) char smem[];

    const int tid  = threadIdx.x;
    const int w    = tid >> 6;        // 0..7
    const int lane = tid & 63;
    const int g    = lane >> 4;
    const int ln   = lane & 15;
    const int qt   = w & 1;           // QK qtile / P row block (2)
    const int js   = w >> 1;          // QK j-subtile (4 x 16 rows)
    const int dsl  = w * 64;          // PV d-slice

    const int batch = blockIdx.x & 7;
    const int qbase = (blockIdx.x >> 3) * BM;

    const char* xq_b = (const char*)(xq + (size_t)batch * SEQ * 512);
    const char* xt_b = (const char*)(xt + (size_t)batch * (size_t)DIM * SEQ);

    // Q fragments (fp8, permuted layout) + C = ||q_fp8||^2 (g-lane-reduced)
    const int qrow = qbase + qt * 16 + ln;
    l2 q8[8];
    {
        const char* qp = xq_b + (size_t)qrow * 512 + g * 16;
        #pragma unroll
        for (int i = 0; i < 8; ++i) q8[i] = *(const l2*)(qp + i * 64);
    }
    float C = 0.f;
    #pragma unroll
    for (int i = 0; i < 8; ++i) {
        union { l2 v; unsigned u[4]; } U; U.v = q8[i];
        #pragma unroll
        for (int j = 0; j < 4; ++j) {
            #pragma unroll
            for (int by = 0; by < 4; ++by) {
                const float f = fp8_dec((U.u[j] >> (8 * by)) & 255u);
                C = fmaf(f, f, C);
            }
        }
    }
    C += __shfl_xor(C, 16);
    C += __shfl_xor(C, 32);

    const bool rm = (mask[(size_t)batch * SEQ + qrow] == 0);

    f32x4 acc[2][4];
    #pragma unroll
    for (int i = 0; i < 2; ++i)
        #pragma unroll
        for (int j = 0; j < 4; ++j) acc[i][j] = (f32x4){0.f, 0.f, 0.f, 0.f};
    float lacc = 0.f;

    const int prow_w = (qt * 16 + ln) * 144 + js * 32 + g * 8;
    const int rowb   = (js * 16 + ln) * 512;
    const int sw     = (ln & 7) << 4;
    // V frag source: per lane 16B at xt[d = dsl + dt*16 + ln][j0 + ks*32 + 8g]
    const char* vsrc = xt_b + (size_t)(dsl + ln) * 4096 + g * 16;

    s16x8 vreg[2][4];   // V reg buffer (tile t), fully static indexing

    auto stageK = [&](int kbuf, int jts) {
        char* bK = smem + kbuf;
        const int j0 = jts * BN;
        #pragma unroll
        for (int i = 0; i < 4; ++i) {            // 2 rows/gload, 8 rows/wave
            const int r0  = w * 8 + i * 2;
            const int row = r0 + (lane >> 5);
            gload_lds16(xq_b + (size_t)(j0 + row) * 512
                             + (((lane & 31) << 4) ^ ((row & 7) << 4)),
                        bK + r0 * 512);
        }
    };
    auto issueV = [&](int jts) {                 // global -> VGPR, no LDS
        const int j0b = jts * BN * 2;            // byte offset in a d-row
        #pragma unroll
        for (int ks = 0; ks < 2; ++ks)
            #pragma unroll
            for (int dt = 0; dt < 4; ++dt)
                vreg[ks][dt] = *(const s16x8*)(vsrc + (size_t)dt * 65536
                                               + j0b + ks * 64);
    };

    // QK(t) -> fixed-m softmax -> P write
    auto qk_sm = [&](int kbuf, int pbuf) {
        const char* bK = smem + kbuf;
        f32x4 sa = (f32x4){0.f, 0.f, 0.f, 0.f};
        f32x4 sb = (f32x4){0.f, 0.f, 0.f, 0.f};
        #pragma unroll
        for (int kk2 = 0; kk2 < 8; ++kk2) {
            l2 kv = *(const l2*)(bK + rowb + ((kk2 * 64 + g * 16) ^ sw));
            sa = __builtin_amdgcn_mfma_f32_16x16x32_fp8_fp8(kv[0], q8[kk2][0], sa, 0, 0, 0);
            sb = __builtin_amdgcn_mfma_f32_16x16x32_fp8_fp8(kv[1], q8[kk2][1], sb, 0, 0, 0);
        }
        const f32x4 s = sa + sb;
        float p0, p1, p2, p3;
        if (rm) {
            p0 = p1 = p2 = p3 = 1.f;
        } else {
            p0 = __expf(s[0] - C); p1 = __expf(s[1] - C);
            p2 = __expf(s[2] - C); p3 = __expf(s[3] - C);
        }
        lacc += (p0 + p1) + (p2 + p3);
        u32x2 pw; pw[0] = pk2(p0, p1); pw[1] = pk2(p2, p3);
        *(u32x2*)(smem + pbuf + prow_w) = pw;
    };

    // PV(t): O += P[t] @ V[t]  (V from vreg)
    auto pv = [&](int pbuf) {
        const char* Pb = smem + pbuf;
        #pragma unroll
        for (int q2 = 0; q2 < 2; ++q2) {
            s16x8 pa0 = *(const s16x8*)(Pb + (q2 * 16 + ln) * 144 + g * 16);
            s16x8 pa1 = *(const s16x8*)(Pb + (q2 * 16 + ln) * 144 + 64 + g * 16);
            #pragma unroll
            for (int dt = 0; dt < 4; ++dt) {
                acc[q2][dt] = __builtin_amdgcn_mfma_f32_16x16x32_bf16(
                    pa0, vreg[0][dt], acc[q2][dt], 0, 0, 0);
                acc[q2][dt] = __builtin_amdgcn_mfma_f32_16x16x32_bf16(
                    pa1, vreg[1][dt], acc[q2][dt], 0, 0, 0);
            }
        }
    };

    // ---- prologue: tile 0 ----
    stageK(KB0, 0);
    asm volatile("s_waitcnt vmcnt(0)" ::: "memory");
    __builtin_amdgcn_sched_barrier(0);
    __builtin_amdgcn_s_barrier();
    __builtin_amdgcn_sched_barrier(0);
    stageK(KB1, 1);
    issueV(0);
    __builtin_amdgcn_s_setprio(1);
    qk_sm(KB0, PB0);
    __builtin_amdgcn_s_setprio(0);
    asm volatile("s_waitcnt lgkmcnt(0)" ::: "memory");
    __builtin_amdgcn_sched_barrier(0);

    // ---- pipelined main loop: PV(t-1) + QK(t) per barrier segment ----
    for (int t = 1; t < NIT; ++t) {
        asm volatile("s_waitcnt vmcnt(0)" ::: "memory");
        __builtin_amdgcn_sched_barrier(0);
        __builtin_amdgcn_s_barrier();
        __builtin_amdgcn_sched_barrier(0);

        const int cur = t & 1;
        if (t + 1 < NIT) stageK(cur ? KB0 : KB1, t + 1);

        __builtin_amdgcn_s_setprio(1);
        pv(cur ? PB0 : PB1);                      // PV(t-1), consumes vreg
        __builtin_amdgcn_s_setprio(0);
        issueV(t);                                // refill vreg (after reads)
        __builtin_amdgcn_s_setprio(1);
        qk_sm(cur ? KB1 : KB0, cur ? PB1 : PB0);  // QK(t) -> P[t]
        __builtin_amdgcn_s_setprio(0);

        asm volatile("s_waitcnt lgkmcnt(0)" ::: "memory");
        __builtin_amdgcn_sched_barrier(0);
    }

    // ---- epilogue: PV(NIT-1) ----
    asm volatile("s_waitcnt vmcnt(0)" ::: "memory");
    __builtin_amdgcn_sched_barrier(0);
    __builtin_amdgcn_s_barrier();
    __builtin_amdgcn_sched_barrier(0);
    pv(PB1);                                      // NIT-1 = 31 -> buf 1

    // ---- l merge: sum g-lanes, then the 4 js-waves sharing each qt ----
    lacc += __shfl_xor(lacc, 16);
    lacc += __shfl_xor(lacc, 32);
    __syncthreads();
    float* lbuf = (float*)(smem + LBO);
    float* linv = (float*)(smem + LIO);
    if (lane < 16) lbuf[w * 16 + ln] = lacc;
    __syncthreads();
    if (w < 2 && lane < 16) {
        const float ltot = lbuf[(w + 0) * 16 + ln] + lbuf[(w + 2) * 16 + ln]
                         + lbuf[(w + 4) * 16 + ln] + lbuf[(w + 6) * 16 + ln];
        linv[w * 16 + ln] = 1.0f / ltot;
    }
    __syncthreads();

    // ---- epilogue store: O[q][d] = acc * linv[q] ----
    float* ob = out + ((size_t)batch * SEQ + qbase) * DIM;
    #pragma unroll
    for (int q2 = 0; q2 < 2; ++q2) {
        const f32x4 iv = *(const f32x4*)(linv + q2 * 16 + g * 4);
        #pragma unroll
        for (int dt = 0; dt < 4; ++dt) {
            const int d = dsl + dt * 16 + ln;
            #pragma unroll
            for (int r = 0; r < 4; ++r) {
                ob[(size_t)(q2 * 16 + 4 * g + r) * DIM + d] = acc[q2][dt][r] * iv[r];
            }
        }
    }
}

extern "C" void kernel_launch(void* const* d_in, const int* in_sizes, int n_in,
                              void* d_out, int out_size, void* d_ws, size_t ws_size,
                              hipStream_t stream) {
    (void)in_sizes; (void)n_in; (void)ws_size; (void)out_size;
    const float* x    = (const float*)d_in[0];
    const int*   mask = (const int*)d_in[1];
    float*       out  = (float*)d_out;
    unsigned short* xt = (unsigned short*)d_ws;                        // 16 MiB
    unsigned char*  xq = (unsigned char*)d_ws
                       + (size_t)BATCH * SEQ * DIM * sizeof(unsigned short); // 8 MiB

    prep_kernel<<<dim3(2048), dim3(256), 0, stream>>>(x, xq, xt);

    (void)hipFuncSetAttribute((const void*)attn_fwd,
                              hipFuncAttributeMaxDynamicSharedMemorySize, LDS_TOTAL);
    attn_fwd<<<dim3(BATCH * (SEQ / BM)), dim3(512), LDS_TOTAL, stream>>>(
        xq, xt, mask, out);
}

// Round 11
// 115.084 us; speedup vs baseline: 2.1260x; 2.1260x over previous
//
#include <hip/hip_runtime.h>

// Flash attention, Q=K=V=x, row-mask. B=8, S=2048, D=512, fp32 in/out.
// R11 = R9 (V in VGPRs, K fp8 in LDS dbuf, P via LDS) with the register
// budget restored to __launch_bounds__(512,2) (256 regs/wave). R9/R10
// proved the pipeline's live state (~150+) spills catastrophically under
// a 128-reg cap; at 256 regs (R8's budget, VGPR_Count=92) it fits.
// LDS = K dbuf 32K + P dbuf 10K + merge ~1K = 43K. 1 block/CU, 8 waves.
// fp8 QK (pair-interleaved cols), fixed-m softmax, masked rows p=1.

constexpr int BATCH = 8;
constexpr int SEQ   = 2048;
constexpr int DIM   = 512;
constexpr int BM    = 64;
constexpr int BN    = 32;
constexpr int NIT   = SEQ / BN;     // 64

// LDS byte offsets
constexpr int KB0 = 0,     KB1 = 16384;     // fp8 Kt[32][512B]
constexpr int PB0 = 32768, PB1 = 37888;     // 64 rows x 80B
constexpr int LBO = 43008, LIO = 43520;
constexpr int LDS_TOTAL = 43776;

typedef float f4    __attribute__((ext_vector_type(4)));
typedef float f32x4 __attribute__((ext_vector_type(4)));
typedef short s16x8 __attribute__((ext_vector_type(8)));
typedef long  l2    __attribute__((ext_vector_type(2)));
typedef unsigned u32x2 __attribute__((ext_vector_type(2)));
typedef unsigned u32x4 __attribute__((ext_vector_type(4)));

#define AS1 __attribute__((address_space(1)))
#define AS3 __attribute__((address_space(3)))

__device__ __forceinline__ unsigned bfr(float x) {   // f32 -> bf16 (RNE)
    unsigned u = __float_as_uint(x);
    return (u + 0x7FFFu + ((u >> 16) & 1u)) >> 16;
}
__device__ __forceinline__ unsigned pk2(float a, float b) {
    return bfr(a) | (bfr(b) << 16);
}
__device__ __forceinline__ void gload_lds16(const void* g, void* l) {
    __builtin_amdgcn_global_load_lds((const AS1 void*)g, (AS3 void*)l, 16, 0, 0);
}
__device__ __forceinline__ float fp8_dec(unsigned byte) {  // e4m3fn -> f32
    const unsigned e = (byte >> 3) & 15u, m = byte & 7u;
    return e ? __uint_as_float(((byte & 128u) << 24) | ((e + 120u) << 23) | (m << 20))
             : 0.f;
}

// ---------------- prep: fp32 -> fp8 (k-pair-interleaved) + bf16 transposed ----
__global__ __launch_bounds__(256)
void prep_kernel(const float* __restrict__ x, unsigned char* __restrict__ xq,
                 unsigned short* __restrict__ xt) {
    __shared__ __align__(16) unsigned short tile[64 * 66];
    const int t   = threadIdx.x;
    const int bid = blockIdx.x;          // 2048 = 8 b * 32 s-tiles * 8 d-tiles
    const int b   = bid >> 8;
    const int rr  = bid & 255;
    const int s0  = (rr >> 3) * 64;
    const int d0  = (rr & 7) * 64;
    const float* xb = x + (size_t)b * SEQ * DIM;

    const int sl = t >> 4, c4 = t & 15;
    // column-permuted fp8 offset for k0 = d0 + c4*4 (e0 in {0,4})
    const int k0 = d0 + c4 * 4;
    const int kk = k0 >> 5, gg = (k0 >> 3) & 3, e0 = k0 & 7;
    const int cp = (kk >> 1) * 64 + gg * 16 + (kk & 1) * 8 + e0;

    #pragma unroll
    for (int k = 0; k < 4; ++k) {
        const int s = sl + k * 16;
        f4 v = *(const f4*)(xb + (size_t)(s0 + s) * DIM + k0);
        int r = __builtin_amdgcn_cvt_pk_fp8_f32(v[0], v[1], 0, false);
        r     = __builtin_amdgcn_cvt_pk_fp8_f32(v[2], v[3], r, true);
        *(int*)(xq + (size_t)(b * SEQ + s0 + s) * 512 + cp) = r;
        tile[(c4 * 4 + 0) * 66 + s] = (unsigned short)bfr(v[0]);
        tile[(c4 * 4 + 1) * 66 + s] = (unsigned short)bfr(v[1]);
        tile[(c4 * 4 + 2) * 66 + s] = (unsigned short)bfr(v[2]);
        tile[(c4 * 4 + 3) * 66 + s] = (unsigned short)bfr(v[3]);
    }
    __syncthreads();
    const int dl = t >> 2, sb = t & 3;
    const unsigned* lp = (const unsigned*)&tile[dl * 66 + sb * 16];
    unsigned short* op = xt + ((size_t)b * DIM + d0 + dl) * SEQ + s0 + sb * 16;
    u32x4 a, c;
    a[0] = lp[0]; a[1] = lp[1]; a[2] = lp[2]; a[3] = lp[3];
    c[0] = lp[4]; c[1] = lp[5]; c[2] = lp[6]; c[3] = lp[7];
    *(u32x4*)op = a;
    *(u32x4*)(op + 8) = c;
}

// ---------------- main attention kernel ----------------
__global__ __launch_bounds__(512, 2)
void attn_fwd(const unsigned char* __restrict__ xq,
              const unsigned short* __restrict__ xt,
              const int* __restrict__ mask,
              float* __restrict__ out) {
    extern __shared__ __align__(16) char smem[];

    const int tid  = threadIdx.x;
    const int w    = tid >> 6;        // 0..7
    const int lane = tid & 63;
    const int g    = lane >> 4;
    const int ln   = lane & 15;
    const int qt   = w & 3;           // QK qtile / P row block
    const int js   = w >> 2;          // QK j-half
    const int dsl  = w * 64;          // PV d-slice

    const int batch = blockIdx.x & 7;
    const int qbase = (blockIdx.x >> 3) * BM;

    const char* xq_b = (const char*)(xq + (size_t)batch * SEQ * 512);
    const char* xt_b = (const char*)(xt + (size_t)batch * (size_t)DIM * SEQ);

    // Q fragments (fp8, permuted layout) + C = ||q_fp8||^2 (g-lane-reduced)
    const int qrow = qbase + qt * 16 + ln;
    l2 q8[8];
    {
        const char* qp = xq_b + (size_t)qrow * 512 + g * 16;
        #pragma unroll
        for (int i = 0; i < 8; ++i) q8[i] = *(const l2*)(qp + i * 64);
    }
    float C = 0.f;
    #pragma unroll
    for (int i = 0; i < 8; ++i) {
        union { l2 v; unsigned u[4]; } U; U.v = q8[i];
        #pragma unroll
        for (int j = 0; j < 4; ++j) {
            #pragma unroll
            for (int by = 0; by < 4; ++by) {
                const float f = fp8_dec((U.u[j] >> (8 * by)) & 255u);
                C = fmaf(f, f, C);
            }
        }
    }
    C += __shfl_xor(C, 16);
    C += __shfl_xor(C, 32);

    const bool rm = (mask[(size_t)batch * SEQ + qrow] == 0);

    f32x4 acc[4][4];
    #pragma unroll
    for (int i = 0; i < 4; ++i)
        #pragma unroll
        for (int j = 0; j < 4; ++j) acc[i][j] = (f32x4){0.f, 0.f, 0.f, 0.f};
    float lacc = 0.f;

    const int prow_w = (qt * 16 + ln) * 80 + js * 32 + g * 8;
    const int rowb   = (js * 16 + ln) * 512;
    const int sw     = (ln & 7) << 4;
    // V frag source: per lane 16B at xt[d = dsl + dt*16 + ln][j0 + 8g .. +8]
    const char* vsrc = xt_b + (size_t)(dsl + ln) * 4096 + g * 16;

    s16x8 vreg[4];   // single reg V buffer (tile t), static-indexed

    auto stageK = [&](int kbuf, int jts) {
        char* bK = smem + kbuf;
        const int j0 = jts * BN;
        #pragma unroll
        for (int i = 0; i < 2; ++i) {            // 2 rows per gload, 4 rows/wave
            const int r0  = w * 4 + i * 2;
            const int row = r0 + (lane >> 5);
            gload_lds16(xq_b + (size_t)(j0 + row) * 512
                             + (((lane & 31) << 4) ^ ((row & 7) << 4)),
                        bK + r0 * 512);
        }
    };
    auto issueV = [&](int jts) {                 // global -> VGPR, no LDS
        const int j0b = jts * BN * 2;            // byte offset in a d-row
        #pragma unroll
        for (int dt = 0; dt < 4; ++dt)
            vreg[dt] = *(const s16x8*)(vsrc + (size_t)dt * 65536 + j0b);
    };

    // QK(t) -> fixed-m softmax -> P write
    auto qk_sm = [&](int kbuf, int pbuf) {
        const char* bK = smem + kbuf;
        f32x4 sa = (f32x4){0.f, 0.f, 0.f, 0.f};
        f32x4 sb = (f32x4){0.f, 0.f, 0.f, 0.f};
        #pragma unroll
        for (int kk2 = 0; kk2 < 8; ++kk2) {
            l2 kv = *(const l2*)(bK + rowb + ((kk2 * 64 + g * 16) ^ sw));
            sa = __builtin_amdgcn_mfma_f32_16x16x32_fp8_fp8(kv[0], q8[kk2][0], sa, 0, 0, 0);
            sb = __builtin_amdgcn_mfma_f32_16x16x32_fp8_fp8(kv[1], q8[kk2][1], sb, 0, 0, 0);
        }
        const f32x4 s = sa + sb;
        float p0, p1, p2, p3;
        if (rm) {
            p0 = p1 = p2 = p3 = 1.f;
        } else {
            p0 = __expf(s[0] - C); p1 = __expf(s[1] - C);
            p2 = __expf(s[2] - C); p3 = __expf(s[3] - C);
        }
        lacc += (p0 + p1) + (p2 + p3);
        u32x2 pw; pw[0] = pk2(p0, p1); pw[1] = pk2(p2, p3);
        *(u32x2*)(smem + pbuf + prow_w) = pw;
    };

    // PV(t): O += P[t] @ V[t]  (V from vreg)
    auto pv = [&](int pbuf) {
        const char* Pb = smem + pbuf;
        s16x8 pa[4];
        #pragma unroll
        for (int q2 = 0; q2 < 4; ++q2)
            pa[q2] = *(const s16x8*)(Pb + (q2 * 16 + ln) * 80 + g * 16);
        #pragma unroll
        for (int q2 = 0; q2 < 4; ++q2)
            #pragma unroll
            for (int dt = 0; dt < 4; ++dt)
                acc[q2][dt] = __builtin_amdgcn_mfma_f32_16x16x32_bf16(
                    pa[q2], vreg[dt], acc[q2][dt], 0, 0, 0);
    };

    // ---- prologue: tile 0 ----
    stageK(KB0, 0);
    asm volatile("s_waitcnt vmcnt(0)" ::: "memory");
    __builtin_amdgcn_sched_barrier(0);
    __builtin_amdgcn_s_barrier();
    __builtin_amdgcn_sched_barrier(0);
    stageK(KB1, 1);
    issueV(0);
    __builtin_amdgcn_s_setprio(1);
    qk_sm(KB0, PB0);
    __builtin_amdgcn_s_setprio(0);
    asm volatile("s_waitcnt lgkmcnt(0)" ::: "memory");
    __builtin_amdgcn_sched_barrier(0);

    // ---- pipelined main loop: PV(t-1) + QK(t) per barrier segment ----
    for (int t = 1; t < NIT; ++t) {
        asm volatile("s_waitcnt vmcnt(0)" ::: "memory");
        __builtin_amdgcn_sched_barrier(0);
        __builtin_amdgcn_s_barrier();
        __builtin_amdgcn_sched_barrier(0);

        const int cur = t & 1;
        if (t + 1 < NIT) stageK(cur ? KB0 : KB1, t + 1);

        __builtin_amdgcn_s_setprio(1);
        pv(cur ? PB0 : PB1);                      // PV(t-1), consumes vreg
        __builtin_amdgcn_s_setprio(0);
        issueV(t);                                // refill vreg (after reads)
        __builtin_amdgcn_s_setprio(1);
        qk_sm(cur ? KB1 : KB0, cur ? PB1 : PB0);  // QK(t) -> P[t]
        __builtin_amdgcn_s_setprio(0);

        asm volatile("s_waitcnt lgkmcnt(0)" ::: "memory");
        __builtin_amdgcn_sched_barrier(0);
    }

    // ---- epilogue: PV(NIT-1) ----
    asm volatile("s_waitcnt vmcnt(0)" ::: "memory");
    __builtin_amdgcn_sched_barrier(0);
    __builtin_amdgcn_s_barrier();
    __builtin_amdgcn_sched_barrier(0);
    pv(PB1);                                      // NIT-1 = 63 -> buf 1

    // ---- l merge across j-halves, then epilogue store ----
    lacc += __shfl_xor(lacc, 16);
    lacc += __shfl_xor(lacc, 32);
    __syncthreads();
    float* lbuf = (float*)(smem + LBO);
    float* linv = (float*)(smem + LIO);
    if (lane < 16) lbuf[w * 16 + ln] = lacc;
    __syncthreads();
    if (w < 4 && lane < 16) {
        const float ltot = lacc + lbuf[(w + 4) * 16 + ln];
        linv[qt * 16 + ln] = 1.0f / ltot;
    }
    __syncthreads();

    float* ob = out + ((size_t)batch * SEQ + qbase) * DIM;
    #pragma unroll
    for (int q2 = 0; q2 < 4; ++q2) {
        const f32x4 iv = *(const f32x4*)(linv + q2 * 16 + g * 4);
        #pragma unroll
        for (int dt = 0; dt < 4; ++dt) {
            const int d = dsl + dt * 16 + ln;
            #pragma unroll
            for (int r = 0; r < 4; ++r) {
                ob[(size_t)(q2 * 16 + 4 * g + r) * DIM + d] = acc[q2][dt][r] * iv[r];
            }
        }
    }
}

extern "C" void kernel_launch(void* const* d_in, const int* in_sizes, int n_in,
                              void* d_out, int out_size, void* d_ws, size_t ws_size,
                              hipStream_t stream) {
    (void)in_sizes; (void)n_in; (void)ws_size; (void)out_size;
    const float* x    = (const float*)d_in[0];
    const int*   mask = (const int*)d_in[1];
    float*       out  = (float*)d_out;
    unsigned short* xt = (unsigned short*)d_ws;                        // 16 MiB
    unsigned char*  xq = (unsigned char*)d_ws
                       + (size_t)BATCH * SEQ * DIM * sizeof(unsigned short); // 8 MiB

    prep_kernel<<<dim3(2048), dim3(256), 0, stream>>>(x, xq, xt);

    (void)hipFuncSetAttribute((const void*)attn_fwd,
                              hipFuncAttributeMaxDynamicSharedMemorySize, LDS_TOTAL);
    attn_fwd<<<dim3(256), dim3(512), LDS_TOTAL, stream>>>(xq, xt, mask, out);
}